// Round 4
// baseline (780.786 us; speedup 1.0000x reference)
//
#include <hip/hip_runtime.h>
#include <hip/hip_cooperative_groups.h>
#include <stdint.h>

namespace cg = cooperative_groups;

#define N_VEC4      8388608u         // 33,554,432 elems / 4 ; norm = 2^25
#define K_SEL       262144u          // MIN_KEPT
#define NSAMP_BLK   16u              // sampling blocks (32768 samples = 1/1024)
#define NCOPY       8u               // global fine-hist replicas
#define FINE_STRIDE 1032u            // 1024 bins + hi slot, padded
#define FIXSH       44
#define FIXMASK     ((1ULL << FIXSH) - 1ULL)

// ws offsets (bytes)
#define OFF_HSAMP 0u                 // 16 * 4096 * 4 = 256 KiB
#define OFF_FINE  262144u            // 8 * 1032 * 8  = 66048 B
#define OFF_CTRL  (262144u + 66048u)

struct Ctrl { unsigned base, top, shift; };

__device__ __forceinline__ float loss_of(float p, float t, float w) {
    float d = p - t;
    return w * (d * d) * 0x1p-25f;   // bitwise == reference w*(p-t)^2 / 2^25
}

// Single kernel, 4 phases. coop=1: grid.sync() between phases (single launch).
// coop=0: phases launched as separate dispatches (fallback), no grid.sync.
__global__ __launch_bounds__(256, 8) void k_all(
    const float4* __restrict__ p, const float4* __restrict__ t,
    const float4* __restrict__ w,
    unsigned* __restrict__ hsamp, unsigned long long* __restrict__ fine,
    Ctrl* __restrict__ ctrl, float* __restrict__ out, int phases, int coop)
{
    __shared__ __align__(16) unsigned shm[4096];   // 16 KiB, aliased per phase
    __shared__ unsigned sufC[257];
    __shared__ unsigned long long sufS[257];
    __shared__ int sBLo, sBHi;
    __shared__ unsigned long long sHiAll;

    cg::grid_group grid = cg::this_grid();
    const unsigned tid = threadIdx.x, bid = blockIdx.x;

    // ---------- phase A: sample hist (blocks 0..15) + zero fine (block 16) --
    if (phases & 1) {
        if (bid < NSAMP_BLK) {
            for (unsigned j = tid; j < 4096; j += 256) shm[j] = 0;
            __syncthreads();
            for (unsigned k = 0; k < 2; ++k) {
                unsigned c = bid * 2u + k;                 // chunk 0..31
                unsigned idx = c * (N_VEC4 / 32u) + tid;   // 256 contiguous float4
                float4 pv = p[idx], tv = t[idx], wv = w[idx];
                atomicAdd(&shm[__float_as_uint(loss_of(pv.x, tv.x, wv.x)) >> 20], 1u);
                atomicAdd(&shm[__float_as_uint(loss_of(pv.y, tv.y, wv.y)) >> 20], 1u);
                atomicAdd(&shm[__float_as_uint(loss_of(pv.z, tv.z, wv.z)) >> 20], 1u);
                atomicAdd(&shm[__float_as_uint(loss_of(pv.w, tv.w, wv.w)) >> 20], 1u);
            }
            __syncthreads();
            for (unsigned j = tid; j < 4096; j += 256) hsamp[bid * 4096u + j] = shm[j];
        } else if (bid == NSAMP_BLK) {
            for (unsigned j = tid; j < NCOPY * FINE_STRIDE; j += 256) fine[j] = 0ull;
        }
    }
    if (coop) grid.sync();

    // ---------- phase B: block 0 picks window [base, top) + fine shift ------
    if ((phases & 2) && bid == 0) {
        for (unsigned j = tid; j < 4096; j += 256) {
            unsigned v = 0;
            for (unsigned h = 0; h < NSAMP_BLK; ++h) v += hsamp[h * 4096u + j];
            shm[j] = v;
        }
        __syncthreads();
        unsigned sv = 0;
        for (int j = 0; j < 16; ++j) sv += shm[tid * 16 + j];
        sufC[tid] = sv;
        if (tid == 0) { sufC[256] = 0; sBLo = 0; sBHi = 2047; }
        __syncthreads();
        for (int off = 1; off < 256; off <<= 1) {            // inclusive suffix scan
            unsigned v = (tid + off < 256) ? sufC[tid + off] : 0u;
            __syncthreads();
            sufC[tid] += v;
            __syncthreads();
        }
        // sample targets (1/1024 sampling): bottom ~1.8K, top ~0.45K full-scale
        const unsigned TLO = 460u, THI = 115u;
        if (sufC[tid] >= TLO && sufC[tid + 1] < TLO) {
            unsigned cum = sufC[tid + 1]; int found = (int)tid * 16;
            for (int b = (int)tid * 16 + 15; b >= (int)tid * 16; --b) {
                cum += shm[b]; if (cum >= TLO) { found = b; break; }
            }
            sBLo = found;
        }
        if (sufC[tid] >= THI && sufC[tid + 1] < THI) {
            unsigned cum = sufC[tid + 1]; int found = (int)tid * 16;
            for (int b = (int)tid * 16 + 15; b >= (int)tid * 16; --b) {
                cum += shm[b]; if (cum >= THI) { found = b; break; }
            }
            sBHi = found;
        }
        __syncthreads();
        if (tid == 0) {
            int blo = sBLo - 1; if (blo < 0) blo = 0;        // ~6-sigma extra margin
            int bhi = sBHi; if (bhi < blo) bhi = blo;
            unsigned base = (unsigned)blo << 20;
            unsigned top  = (unsigned)(bhi + 1) << 20;
            unsigned span = top - base;
            unsigned shift = 10;
            while ((span >> shift) > 1024u) ++shift;         // <=1024 fine bins
            ctrl->base = base; ctrl->top = top; ctrl->shift = shift;
        }
    }
    if (coop) grid.sync();

    // ---------- phase C: stream 384 MB; LDS-only binning; epilogue merge ----
    if (phases & 4) {
        const unsigned base = ctrl->base, top = ctrl->top, shift = ctrl->shift;
        unsigned* fc = shm;                       // [0..1023]   counts
        float* fs = (float*)&shm[1024];           // [1024..2047] sums
        for (unsigned j = tid; j < 2050; j += 256) shm[j] = 0;   // + hiC, hiS
        __syncthreads();
        const unsigned stride = gridDim.x * 256u;
        for (unsigned i = bid * 256u + tid; i < N_VEC4; i += stride) {
            float4 pv = p[i], tv = t[i], wv = w[i];
            float l0 = loss_of(pv.x, tv.x, wv.x);
            float l1 = loss_of(pv.y, tv.y, wv.y);
            float l2 = loss_of(pv.z, tv.z, wv.z);
            float l3 = loss_of(pv.w, tv.w, wv.w);
            unsigned b0 = __float_as_uint(l0), b1 = __float_as_uint(l1);
            unsigned b2 = __float_as_uint(l2), b3 = __float_as_uint(l3);
            // no-return LDS atomics: no dependency chain, loads keep streaming
            if (b0 >= base) { if (b0 >= top) { atomicAdd(&shm[2048], 1u); atomicAdd((float*)&shm[2049], l0); } else { unsigned ix = (b0 - base) >> shift; atomicAdd(&fc[ix], 1u); atomicAdd(&fs[ix], l0); } }
            if (b1 >= base) { if (b1 >= top) { atomicAdd(&shm[2048], 1u); atomicAdd((float*)&shm[2049], l1); } else { unsigned ix = (b1 - base) >> shift; atomicAdd(&fc[ix], 1u); atomicAdd(&fs[ix], l1); } }
            if (b2 >= base) { if (b2 >= top) { atomicAdd(&shm[2048], 1u); atomicAdd((float*)&shm[2049], l2); } else { unsigned ix = (b2 - base) >> shift; atomicAdd(&fc[ix], 1u); atomicAdd(&fs[ix], l2); } }
            if (b3 >= base) { if (b3 >= top) { atomicAdd(&shm[2048], 1u); atomicAdd((float*)&shm[2049], l3); } else { unsigned ix = (b3 - base) >> shift; atomicAdd(&fc[ix], 1u); atomicAdd(&fs[ix], l3); } }
        }
        __syncthreads();
        unsigned long long* myf = fine + (size_t)(bid & (NCOPY - 1u)) * FINE_STRIDE;
        for (unsigned j = tid; j < 1024; j += 256) {
            unsigned c = fc[j];
            if (c) atomicAdd(&myf[j],
                ((unsigned long long)c << FIXSH) | (unsigned long long)(fs[j] * 0x1p44f));
        }
        if (tid == 0) {
            unsigned c = shm[2048];
            if (c) atomicAdd(&myf[1024],
                ((unsigned long long)c << FIXSH) |
                (unsigned long long)(*(float*)&shm[2049] * 0x1p44f));
        }
    }
    if (coop) grid.sync();

    // ---------- phase D: block 0 folds copies, selects, writes scalar -------
    if ((phases & 8) && bid == 0) {
        unsigned* cnt = shm;                                  // [0..1023]
        unsigned long long* sums = (unsigned long long*)&shm[1024];  // 8 KiB
        for (unsigned j = tid; j < 1024; j += 256) {
            unsigned long long a = 0;
            for (unsigned c = 0; c < NCOPY; ++c) a += fine[c * FINE_STRIDE + j];
            cnt[j] = (unsigned)(a >> FIXSH);
            sums[j] = a & FIXMASK;
        }
        if (tid == 0) {
            unsigned long long a = 0;
            for (unsigned c = 0; c < NCOPY; ++c) a += fine[c * FINE_STRIDE + 1024];
            sHiAll = a;
        }
        __syncthreads();
        unsigned sc = 0; unsigned long long ssum = 0;
        for (int j = 0; j < 4; ++j) { sc += cnt[tid * 4 + j]; ssum += sums[tid * 4 + j]; }
        sufC[tid] = sc; sufS[tid] = ssum;
        if (tid == 0) { sufC[256] = 0; sufS[256] = 0; }
        __syncthreads();
        for (int off = 1; off < 256; off <<= 1) {
            unsigned v = 0; unsigned long long vs = 0;
            if (tid + off < 256) { v = sufC[tid + off]; vs = sufS[tid + off]; }
            __syncthreads();
            sufC[tid] += v; sufS[tid] += vs;
            __syncthreads();
        }
        unsigned A = (unsigned)(sHiAll >> FIXSH);
        unsigned long long SA = sHiAll & FIXMASK;
        if (tid == 0 && A >= K_SEL)                          // unreachable guard
            out[0] = (float)((double)SA * 0x1p-44 / (double)(A ? A : 1u));
        if (tid == 0 && A < K_SEL && A + sufC[0] < K_SEL) {  // unreachable guard
            double bf = (double)__uint_as_float(ctrl->base);
            double tot = ((double)SA + (double)sufS[0]) * 0x1p-44
                       + (double)(K_SEL - A - sufC[0]) * bf;
            out[0] = (float)(tot / (double)K_SEL);
        }
        if (A < K_SEL && A + sufC[tid] >= K_SEL && A + sufC[tid + 1] < K_SEL) {
            unsigned cumAb = A + sufC[tid + 1];
            unsigned long long sumAb = SA + sufS[tid + 1];
            for (int b = (int)tid * 4 + 3; b >= (int)tid * 4; --b) {
                unsigned cb = cnt[b];
                if (cumAb + cb >= K_SEL) {
                    unsigned r = K_SEL - cumAb;
                    double mean = (double)sums[b] / (double)(cb ? cb : 1u);
                    double tot = (double)sumAb + (double)r * mean;
                    out[0] = (float)(tot * 0x1p-44 / (double)K_SEL);
                    break;
                }
                cumAb += cb; sumAb += sums[b];
            }
        }
    }
}

extern "C" void kernel_launch(void* const* d_in, const int* in_sizes, int n_in,
                              void* d_out, int out_size, void* d_ws, size_t ws_size,
                              hipStream_t stream) {
    const float4* p = (const float4*)d_in[0];
    const float4* t = (const float4*)d_in[1];
    const float4* w = (const float4*)d_in[2];
    char* ws = (char*)d_ws;
    unsigned* hsamp = (unsigned*)(ws + OFF_HSAMP);
    unsigned long long* fine = (unsigned long long*)(ws + OFF_FINE);
    Ctrl* ctrl = (Ctrl*)(ws + OFF_CTRL);
    float* outp = (float*)d_out;

    // co-resident grid size: blocks/CU from occupancy query x 256 CUs, cap 2048
    int maxB = 0;
    hipError_t qe = hipOccupancyMaxActiveBlocksPerMultiprocessor(
        &maxB, (const void*)k_all, 256, 0);
    int nblk = 2048;
    if (qe == hipSuccess && maxB > 0) {
        int cap = maxB * 256;           // 256 = CU count on MI355X
        if (cap < nblk) nblk = cap;
    }
    if (nblk < 32) nblk = 32;

    int phases = 15, coop = 1;
    void* args[] = { (void*)&p, (void*)&t, (void*)&w, (void*)&hsamp,
                     (void*)&fine, (void*)&ctrl, (void*)&outp,
                     (void*)&phases, (void*)&coop };
    hipError_t e = hipLaunchCooperativeKernel((const void*)k_all, dim3(nblk),
                                              dim3(256), args, 0, stream);
    if (e != hipSuccess) {
        (void)hipGetLastError();
        // fallback: phases as separate dispatches (stream order gives visibility)
        k_all<<<17,   256, 0, stream>>>(p, t, w, hsamp, fine, ctrl, outp, 1, 0);
        k_all<<<1,    256, 0, stream>>>(p, t, w, hsamp, fine, ctrl, outp, 2, 0);
        k_all<<<2048, 256, 0, stream>>>(p, t, w, hsamp, fine, ctrl, outp, 4, 0);
        k_all<<<1,    256, 0, stream>>>(p, t, w, hsamp, fine, ctrl, outp, 8, 0);
    }
}